// Round 5
// baseline (380.300 us; speedup 1.0000x reference)
//
#include <hip/hip_runtime.h>

typedef __bf16 bf16;
typedef __bf16 bf16x4 __attribute__((ext_vector_type(4)));
typedef __bf16 bf16x8 __attribute__((ext_vector_type(8)));
typedef float f32x4 __attribute__((ext_vector_type(4)));

#define MFMA16(a, b, c) __builtin_amdgcn_mfma_f32_16x16x32_bf16((a), (b), (c), 0, 0, 0)

// 0.125 (attn scale) * log2(e): folded into Q projection so softmax is exp2(s).
#define QSCALE 0.18033688011112042f

__device__ inline bf16x8 cvt8(float4 a, float4 b) {
    bf16x8 v;
    v[0] = (bf16)a.x; v[1] = (bf16)a.y; v[2] = (bf16)a.z; v[3] = (bf16)a.w;
    v[4] = (bf16)b.x; v[5] = (bf16)b.y; v[6] = (bf16)b.z; v[7] = (bf16)b.w;
    return v;
}

// ---------------------------------------------------------------------------
// fp32 -> bf16 conversion (weights): 8 elems/thread, n multiple of 2048.
// ---------------------------------------------------------------------------
__global__ __launch_bounds__(256) void cvt_kernel(
    const float* __restrict__ src, bf16* __restrict__ dst, int n)
{
    int i = (blockIdx.x * 256 + threadIdx.x) * 8;
    if (i < n) {
        float4 a = *(const float4*)&src[i];
        float4 b = *(const float4*)&src[i + 4];
        *(bf16x8*)&dst[i] = cvt8(a, b);
    }
}

// ---------------------------------------------------------------------------
// Fused QKV projection. grid.x = proj*8 + col-block, grid.y = row-block.
// Tile 128x128x64, 4 waves, register-prefetched staging (A fp32 w/ cvt,
// B bf16 pre-converted). proj0 -> Qp (scaled), proj1 -> Kp, proj2 -> Vt
// [bh][d][t64*64+kv'] with kv' = (s&15)*4 + (s>>4) (s = tok&63), written
// coalesced via an LDS transpose that reuses the staging buffers.
// ---------------------------------------------------------------------------
__global__ __launch_bounds__(256) void qkv_gemm(
    const float* __restrict__ q, const float* __restrict__ k,
    const float* __restrict__ v,
    const bf16* __restrict__ wq, const float* __restrict__ bq,
    const bf16* __restrict__ wk, const float* __restrict__ bk,
    const bf16* __restrict__ wv, const float* __restrict__ bv,
    bf16* __restrict__ Qp, bf16* __restrict__ Kp, bf16* __restrict__ Vt)
{
    __shared__ __align__(16) bf16 sm[128 * 72 * 2];  // As | Bs ; Ts aliases
    bf16* As = sm;
    bf16* Bs = sm + 128 * 72;
    bf16* Ts = sm;                                   // [128 col][132] transpose

    const int proj = blockIdx.x >> 3;
    const float* A    = proj == 0 ? q  : proj == 1 ? k  : v;
    const bf16*  B    = proj == 0 ? wq : proj == 1 ? wk : wv;
    const float* bias = proj == 0 ? bq : proj == 1 ? bk : bv;

    const int tid  = threadIdx.x;
    const int lane = tid & 63;
    const int w    = tid >> 6;
    const int g    = lane >> 4;
    const int ln   = lane & 15;
    const int m0   = blockIdx.y * 128;
    const int n0   = (blockIdx.x & 7) * 128;
    const int rowb = (w & 1) * 64;
    const int colb = (w >> 1) * 64;

    const int srow = tid >> 3, skc = (tid & 7) << 3;   // this thread's chunk

    float4 ra[4][2];
    uint4  rb[4];
    {
        for (int i = 0; i < 4; ++i) {
            const float* p = &A[(size_t)(m0 + srow + 32 * i) * 1024 + skc];
            ra[i][0] = *(const float4*)p;
            ra[i][1] = *(const float4*)(p + 4);
            rb[i] = *(const uint4*)&B[(size_t)(n0 + srow + 32 * i) * 1024 + skc];
        }
    }

    f32x4 acc[4][4] = {};

    for (int k0 = 0; k0 < 1024; k0 += 64) {
        for (int i = 0; i < 4; ++i) {
            *(bf16x8*)&As[(srow + 32 * i) * 72 + skc] = cvt8(ra[i][0], ra[i][1]);
            *(uint4*)&Bs[(srow + 32 * i) * 72 + skc] = rb[i];
        }
        if (k0 + 64 < 1024) {   // prefetch next tile (in flight during MFMA)
            for (int i = 0; i < 4; ++i) {
                const float* p = &A[(size_t)(m0 + srow + 32 * i) * 1024 + k0 + 64 + skc];
                ra[i][0] = *(const float4*)p;
                ra[i][1] = *(const float4*)(p + 4);
                rb[i] = *(const uint4*)&B[(size_t)(n0 + srow + 32 * i) * 1024 + k0 + 64 + skc];
            }
        }
        __syncthreads();
        for (int ks = 0; ks < 2; ++ks) {
            bf16x8 af[4], bfm[4];
            for (int mi = 0; mi < 4; ++mi)
                af[mi] = *(const bf16x8*)&As[(rowb + mi * 16 + ln) * 72 + ks * 32 + g * 8];
            for (int ni = 0; ni < 4; ++ni)
                bfm[ni] = *(const bf16x8*)&Bs[(colb + ni * 16 + ln) * 72 + ks * 32 + g * 8];
            for (int mi = 0; mi < 4; ++mi)
                for (int ni = 0; ni < 4; ++ni)
                    acc[mi][ni] = MFMA16(af[mi], bfm[ni], acc[mi][ni]);
        }
        __syncthreads();
    }

    if (proj != 2) {
        for (int mi = 0; mi < 4; ++mi) {
            for (int ni = 0; ni < 4; ++ni) {
                int col = n0 + colb + ni * 16 + ln;
                float bv_ = bias[col];
                int rowbase = m0 + rowb + mi * 16 + g * 4;
                if (proj == 0) {
                    for (int r = 0; r < 4; ++r)
                        Qp[(size_t)(rowbase + r) * 1024 + col] =
                            (bf16)((acc[mi][ni][r] + bv_) * QSCALE);
                } else {
                    for (int r = 0; r < 4; ++r)
                        Kp[(size_t)(rowbase + r) * 1024 + col] =
                            (bf16)(acc[mi][ni][r] + bv_);
                }
            }
        }
    } else {
        // transpose through LDS: Ts[col][tok_local], then coalesced kv'-stores
        for (int mi = 0; mi < 4; ++mi) {
            for (int ni = 0; ni < 4; ++ni) {
                int col = colb + ni * 16 + ln;
                float bv_ = bias[n0 + col];
                int row = rowb + mi * 16 + g * 4;
                bf16x4 pk;
                for (int r = 0; r < 4; ++r) pk[r] = (bf16)(acc[mi][ni][r] + bv_);
                *(bf16x4*)&Ts[col * 132 + row] = pk;
            }
        }
        __syncthreads();
        const int bidx = m0 >> 11;
        const int tok0 = m0 & 2047;        // token offset WITHIN batch (r4 bug: used m0)
        for (int i = 0; i < 8; ++i) {
            int c    = tid + 256 * i;          // chunk id 0..2047
            int col  = c >> 4;
            int t64  = (c >> 3) & 1;
            int cc   = c & 7;                  // kv'-chunk
            int gcol = n0 + col;
            union { bf16 e[8]; uint4 u; } tmp;
            for (int j = 0; j < 8; ++j) {
                int s = 2 * cc + (j >> 2) + ((j & 3) << 4);
                tmp.e[j] = Ts[col * 132 + t64 * 64 + s];
            }
            size_t dst = ((size_t)(bidx * 16 + (gcol >> 6)) * 64 + (gcol & 63)) * 2048
                         + tok0 + t64 * 64 + cc * 8;
            *(uint4*)&Vt[dst] = tmp.u;
        }
    }
}

// ---------------------------------------------------------------------------
// Output projection: C[4096,1024] fp32 = Ctx(bf16) @ wo^T(bf16) + bo.
// Tile 128x128x64, register-prefetched, grid (8,32) = 256 blocks.
// ---------------------------------------------------------------------------
__global__ __launch_bounds__(256) void gemm_out(
    const bf16* __restrict__ A, const bf16* __restrict__ B,
    const float* __restrict__ bias, float* __restrict__ C)
{
    __shared__ __align__(16) bf16 As[128 * 72];
    __shared__ __align__(16) bf16 Bs[128 * 72];

    const int tid  = threadIdx.x;
    const int lane = tid & 63;
    const int w    = tid >> 6;
    const int g    = lane >> 4;
    const int ln   = lane & 15;
    const int m0   = blockIdx.y * 128;
    const int n0   = blockIdx.x * 128;
    const int rowb = (w & 1) * 64;
    const int colb = (w >> 1) * 64;
    const int srow = tid >> 3, skc = (tid & 7) << 3;

    uint4 ra[4], rb[4];
    for (int i = 0; i < 4; ++i) {
        ra[i] = *(const uint4*)&A[(size_t)(m0 + srow + 32 * i) * 1024 + skc];
        rb[i] = *(const uint4*)&B[(size_t)(n0 + srow + 32 * i) * 1024 + skc];
    }

    f32x4 acc[4][4] = {};

    for (int k0 = 0; k0 < 1024; k0 += 64) {
        for (int i = 0; i < 4; ++i) {
            *(uint4*)&As[(srow + 32 * i) * 72 + skc] = ra[i];
            *(uint4*)&Bs[(srow + 32 * i) * 72 + skc] = rb[i];
        }
        if (k0 + 64 < 1024) {
            for (int i = 0; i < 4; ++i) {
                ra[i] = *(const uint4*)&A[(size_t)(m0 + srow + 32 * i) * 1024 + k0 + 64 + skc];
                rb[i] = *(const uint4*)&B[(size_t)(n0 + srow + 32 * i) * 1024 + k0 + 64 + skc];
            }
        }
        __syncthreads();
        for (int ks = 0; ks < 2; ++ks) {
            bf16x8 af[4], bfm[4];
            for (int mi = 0; mi < 4; ++mi)
                af[mi] = *(const bf16x8*)&As[(rowb + mi * 16 + ln) * 72 + ks * 32 + g * 8];
            for (int ni = 0; ni < 4; ++ni)
                bfm[ni] = *(const bf16x8*)&Bs[(colb + ni * 16 + ln) * 72 + ks * 32 + g * 8];
            for (int mi = 0; mi < 4; ++mi)
                for (int ni = 0; ni < 4; ++ni)
                    acc[mi][ni] = MFMA16(af[mi], bfm[ni], acc[mi][ni]);
        }
        __syncthreads();
    }

    for (int mi = 0; mi < 4; ++mi) {
        for (int ni = 0; ni < 4; ++ni) {
            int col = n0 + colb + ni * 16 + ln;
            float bv_ = bias[col];
            int rowbase = m0 + rowb + mi * 16 + g * 4;
            for (int r = 0; r < 4; ++r)
                C[(size_t)(rowbase + r) * 1024 + col] = acc[mi][ni][r] + bv_;
        }
    }
}

// ---------------------------------------------------------------------------
// Flash attention (no-max softmax, logits pre-scaled by 0.125*log2e -> exp2;
// |s| < ~4 so no overflow; softmax shift-invariance makes it exact).
// V is pre-permuted per 64-token tile (kv' = (s&15)*4 + (s>>4)); P is packed
// as bf16x4 b64-stores at [qrow][slot], slot = ln ^ ((qrow&7)<<1) xor-swizzle
// (conflict-optimal b64 writes + b128 reads). K/V staging register-prefetched.
// LDS 36864 B -> 4 blocks/CU. Ps aliases the Q staging buffer.
// ---------------------------------------------------------------------------
__global__ __launch_bounds__(256) void attn_kernel(
    const bf16* __restrict__ Qp, const bf16* __restrict__ Kp,
    const bf16* __restrict__ Vt, bf16* __restrict__ Ctx)
{
    __shared__ __align__(16) bf16 smem[9216 + 4608 + 4608];
    bf16* Ps = smem;               // [128][64] swizzled (8192 elems used)
    bf16* Qs = smem;               // [128][72] staging only (aliased)
    bf16* Ks = smem + 9216;        // [64][72]  [kv][d]
    bf16* Vs = Ks + 4608;          // [64][72]  [d][kv']

    const int tid  = threadIdx.x;
    const int lane = tid & 63;
    const int w    = tid >> 6;
    const int g    = lane >> 4;
    const int ln   = lane & 15;
    const size_t rowQ0 = (size_t)(blockIdx.y >> 4) * 2048 + blockIdx.x * 128;
    const size_t rowK0 = (size_t)(blockIdx.y >> 4) * 2048;
    const int hcol = (blockIdx.y & 15) * 64;
    const bf16* VtB = Vt + (size_t)blockIdx.y * 64 * 2048;

    // stage Q tile 128x64 and preload A-frags
    for (int i = 0; i < 4; ++i) {
        int c = tid + 256 * i;
        int row = c >> 3, dc = (c & 7) << 3;
        *(uint4*)&Qs[row * 72 + dc] =
            *(const uint4*)&Qp[(rowQ0 + row) * 1024 + hcol + dc];
    }
    __syncthreads();
    bf16x8 qf[2][2];
    for (int mi = 0; mi < 2; ++mi)
        for (int ks = 0; ks < 2; ++ks)
            qf[mi][ks] = *(const bf16x8*)&Qs[(w * 32 + mi * 16 + ln) * 72 + ks * 32 + g * 8];

    f32x4 oacc[2][4] = {};
    float l_part[2][4] = {};

    const int sr = tid >> 3, sdc = (tid & 7) << 3;  // staging coords (2 iters)
    uint4 rk[2], rv[2];
    for (int i = 0; i < 2; ++i) {
        rk[i] = *(const uint4*)&Kp[(rowK0 + sr + 32 * i) * 1024 + hcol + sdc];
        rv[i] = *(const uint4*)&VtB[(size_t)(sr + 32 * i) * 2048 + sdc];
    }

    for (int t = 0; t < 32; ++t) {
        __syncthreads();   // prior tile fully consumed (and t=0: qf preload done)
        for (int i = 0; i < 2; ++i) {
            *(uint4*)&Ks[(sr + 32 * i) * 72 + sdc] = rk[i];
            *(uint4*)&Vs[(sr + 32 * i) * 72 + sdc] = rv[i];
        }
        if (t < 31) {
            for (int i = 0; i < 2; ++i) {
                rk[i] = *(const uint4*)&Kp[(rowK0 + (t + 1) * 64 + sr + 32 * i) * 1024 + hcol + sdc];
                rv[i] = *(const uint4*)&VtB[(size_t)(sr + 32 * i) * 2048 + (t + 1) * 64 + sdc];
            }
        }
        __syncthreads();

        // S = Q K^T (pre-scaled)
        f32x4 sf[2][4] = {};
        for (int ks = 0; ks < 2; ++ks) {
            bf16x8 kf[4];
            for (int nj = 0; nj < 4; ++nj)
                kf[nj] = *(const bf16x8*)&Ks[(nj * 16 + ln) * 72 + ks * 32 + g * 8];
            for (int mi = 0; mi < 2; ++mi)
                for (int nj = 0; nj < 4; ++nj)
                    sf[mi][nj] = MFMA16(qf[mi][ks], kf[nj], sf[mi][nj]);
        }

        // P = exp2(S), packed b64 store at kv' = ln*4 + nj (wave-private rows)
        for (int mi = 0; mi < 2; ++mi) {
            for (int r = 0; r < 4; ++r) {
                float p0 = __builtin_amdgcn_exp2f(sf[mi][0][r]);
                float p1 = __builtin_amdgcn_exp2f(sf[mi][1][r]);
                float p2 = __builtin_amdgcn_exp2f(sf[mi][2][r]);
                float p3 = __builtin_amdgcn_exp2f(sf[mi][3][r]);
                l_part[mi][r] += (p0 + p1) + (p2 + p3);
                int qrow = w * 32 + mi * 16 + g * 4 + r;
                int slot = ln ^ ((qrow & 7) << 1);
                bf16x4 pk;
                pk[0] = (bf16)p0; pk[1] = (bf16)p1; pk[2] = (bf16)p2; pk[3] = (bf16)p3;
                *(bf16x4*)&Ps[qrow * 64 + slot * 4] = pk;
            }
        }

        // O += P V   (Ps read in A-layout over kv'; Vs is kv'-ordered)
        for (int ks = 0; ks < 2; ++ks) {
            bf16x8 pf[2], vf[4];
            for (int mi = 0; mi < 2; ++mi) {
                int row = w * 32 + mi * 16 + ln;
                int p = (ks * 8 + g * 2) ^ ((row & 7) << 1);
                pf[mi] = *(const bf16x8*)&Ps[row * 64 + p * 4];
            }
            for (int nd = 0; nd < 4; ++nd)
                vf[nd] = *(const bf16x8*)&Vs[(nd * 16 + ln) * 72 + ks * 32 + g * 8];
            for (int mi = 0; mi < 2; ++mi)
                for (int nd = 0; nd < 4; ++nd)
                    oacc[mi][nd] = MFMA16(pf[mi], vf[nd], oacc[mi][nd]);
        }
    }

    // epilogue: row-sum reduction (16-lane groups), normalize, store
    for (int mi = 0; mi < 2; ++mi) {
        for (int r = 0; r < 4; ++r) {
            float l = l_part[mi][r];
            for (int off = 8; off >= 1; off >>= 1)
                l += __shfl_xor(l, off, 64);
            float inv = 1.0f / l;
            size_t row = rowQ0 + w * 32 + mi * 16 + g * 4 + r;
            for (int nd = 0; nd < 4; ++nd)
                Ctx[row * 1024 + hcol + nd * 16 + ln] = (bf16)(oacc[mi][nd][r] * inv);
        }
    }
}

extern "C" void kernel_launch(void* const* d_in, const int* in_sizes, int n_in,
                              void* d_out, int out_size, void* d_ws, size_t ws_size,
                              hipStream_t stream)
{
    const float* q  = (const float*)d_in[0];
    const float* k  = (const float*)d_in[1];
    const float* v  = (const float*)d_in[2];
    const float* wq = (const float*)d_in[3];
    const float* bq = (const float*)d_in[4];
    const float* wk = (const float*)d_in[5];
    const float* bk = (const float*)d_in[6];
    const float* wv = (const float*)d_in[7];
    const float* bv = (const float*)d_in[8];
    const float* wo = (const float*)d_in[9];
    const float* bo = (const float*)d_in[10];
    float* out = (float*)d_out;

    const int M = 4096, D = 1024;
    bf16* Qp = (bf16*)d_ws;                 // 8 MB
    bf16* Kp = Qp + (size_t)M * D;          // 8 MB
    bf16* Vt = Kp + (size_t)M * D;          // 8 MB, [bh][d][tok' (kv'-permuted)]
    bf16* Ctx = Qp;    // alias: each attn block overwrites only its consumed Q rows
    bf16* wob = Kp;    // Kp is dead after attn -> holds bf16 wo for gemm_out

    // bf16 weight scratch lives in d_out (16 MB; fully overwritten by gemm_out)
    bf16* wqb = (bf16*)d_out;               // 2 MB
    bf16* wkb = wqb + (size_t)D * D;        // 2 MB
    bf16* wvb = wkb + (size_t)D * D;        // 2 MB

    cvt_kernel<<<512, 256, 0, stream>>>(wq, wqb, D * D);
    cvt_kernel<<<512, 256, 0, stream>>>(wk, wkb, D * D);
    cvt_kernel<<<512, 256, 0, stream>>>(wv, wvb, D * D);
    qkv_gemm<<<dim3(24, 32), 256, 0, stream>>>(q, k, v, wqb, bq, wkb, bk, wvb, bv,
                                               Qp, Kp, Vt);
    attn_kernel<<<dim3(16, 32), 256, 0, stream>>>(Qp, Kp, Vt, Ctx);
    cvt_kernel<<<512, 256, 0, stream>>>(wo, wob, D * D);   // into dead Kp
    gemm_out<<<dim3(8, 32), 256, 0, stream>>>(Ctx, wob, bo, out);
}

// Round 6
// 356.502 us; speedup vs baseline: 1.0668x; 1.0668x over previous
//
#include <hip/hip_runtime.h>

typedef __bf16 bf16;
typedef __bf16 bf16x4 __attribute__((ext_vector_type(4)));
typedef __bf16 bf16x8 __attribute__((ext_vector_type(8)));
typedef float f32x4 __attribute__((ext_vector_type(4)));

#define MFMA16(a, b, c) __builtin_amdgcn_mfma_f32_16x16x32_bf16((a), (b), (c), 0, 0, 0)

// 0.125 (attn scale) * log2(e): folded into Q projection so softmax is exp2(s).
#define QSCALE 0.18033688011112042f

__device__ inline bf16x8 cvt8(float4 a, float4 b) {
    bf16x8 v;
    v[0] = (bf16)a.x; v[1] = (bf16)a.y; v[2] = (bf16)a.z; v[3] = (bf16)a.w;
    v[4] = (bf16)b.x; v[5] = (bf16)b.y; v[6] = (bf16)b.z; v[7] = (bf16)b.w;
    return v;
}

// ---------------------------------------------------------------------------
// fp32 -> bf16: 3 weight matrices in one dispatch (blockIdx.y selects).
// ---------------------------------------------------------------------------
__global__ __launch_bounds__(256) void cvt3_kernel(
    const float* __restrict__ s0, bf16* __restrict__ d0,
    const float* __restrict__ s1, bf16* __restrict__ d1,
    const float* __restrict__ s2, bf16* __restrict__ d2)
{
    const float* src = blockIdx.y == 0 ? s0 : blockIdx.y == 1 ? s1 : s2;
    bf16*        dst = blockIdx.y == 0 ? d0 : blockIdx.y == 1 ? d1 : d2;
    int i = (blockIdx.x * 256 + threadIdx.x) * 8;
    float4 a = *(const float4*)&src[i];
    float4 b = *(const float4*)&src[i + 4];
    *(bf16x8*)&dst[i] = cvt8(a, b);
}

__global__ __launch_bounds__(256) void cvt_kernel(
    const float* __restrict__ src, bf16* __restrict__ dst, int n)
{
    int i = (blockIdx.x * 256 + threadIdx.x) * 8;
    if (i < n) {
        float4 a = *(const float4*)&src[i];
        float4 b = *(const float4*)&src[i + 4];
        *(bf16x8*)&dst[i] = cvt8(a, b);
    }
}

// ---------------------------------------------------------------------------
// Fused QKV projection, 1-D grid of 768 with XCD swizzle: all 8 col-blocks of
// one (proj,row) share id%8 -> same XCD -> A-slab shared in that L2.
// K-loop pipeline: sync; LDS-store(regs); sync; issue loads(t+1); MFMA.
// (Loads AFTER the barrier: compiler drains vmcnt(0) at every s_barrier, so
//  loads issued before it would serialize load(t+1) -> compute(t) — the r5 bug.)
// proj0 -> Qp (scaled), proj1 -> Kp, proj2 -> Vt[bh][d][t64*64+kv'] with
// kv' = (s&15)*4 + (s>>4), via LDS transpose (coalesced 16B stores).
// ---------------------------------------------------------------------------
__global__ __launch_bounds__(256) void qkv_gemm(
    const float* __restrict__ q, const float* __restrict__ k,
    const float* __restrict__ v,
    const bf16* __restrict__ wq, const float* __restrict__ bq,
    const bf16* __restrict__ wk, const float* __restrict__ bk,
    const bf16* __restrict__ wv, const float* __restrict__ bv,
    bf16* __restrict__ Qp, bf16* __restrict__ Kp, bf16* __restrict__ Vt)
{
    __shared__ __align__(16) bf16 sm[128 * 72 * 2];  // As | Bs ; Ts aliases
    bf16* As = sm;
    bf16* Bs = sm + 128 * 72;
    bf16* Ts = sm;                                   // [128 col][132] transpose

    // XCD swizzle decode
    const int id  = blockIdx.x;
    const int pr  = (id >> 6) * 8 + (id & 7);        // proj*32+row, 0..95
    const int cb  = (id >> 3) & 7;
    const int proj = pr >> 5;
    const int m0  = (pr & 31) * 128;
    const int n0  = cb * 128;

    const float* A    = proj == 0 ? q  : proj == 1 ? k  : v;
    const bf16*  B    = proj == 0 ? wq : proj == 1 ? wk : wv;
    const float* bias = proj == 0 ? bq : proj == 1 ? bk : bv;

    const int tid  = threadIdx.x;
    const int lane = tid & 63;
    const int w    = tid >> 6;
    const int g    = lane >> 4;
    const int ln   = lane & 15;
    const int rowb = (w & 1) * 64;
    const int colb = (w >> 1) * 64;
    const int srow = tid >> 3, skc = (tid & 7) << 3;

    float4 ra[4][2];
    uint4  rb[4];
    for (int i = 0; i < 4; ++i) {
        const float* p = &A[(size_t)(m0 + srow + 32 * i) * 1024 + skc];
        ra[i][0] = *(const float4*)p;
        ra[i][1] = *(const float4*)(p + 4);
        rb[i] = *(const uint4*)&B[(size_t)(n0 + srow + 32 * i) * 1024 + skc];
    }

    f32x4 acc[4][4] = {};

    for (int k0 = 0; k0 < 1024; k0 += 64) {
        __syncthreads();                    // prev MFMA done reading LDS
        for (int i = 0; i < 4; ++i) {
            *(bf16x8*)&As[(srow + 32 * i) * 72 + skc] = cvt8(ra[i][0], ra[i][1]);
            *(uint4*)&Bs[(srow + 32 * i) * 72 + skc] = rb[i];
        }
        __syncthreads();                    // LDS visible
        if (k0 + 64 < 1024) {               // in flight during MFMA below
            for (int i = 0; i < 4; ++i) {
                const float* p = &A[(size_t)(m0 + srow + 32 * i) * 1024 + k0 + 64 + skc];
                ra[i][0] = *(const float4*)p;
                ra[i][1] = *(const float4*)(p + 4);
                rb[i] = *(const uint4*)&B[(size_t)(n0 + srow + 32 * i) * 1024 + k0 + 64 + skc];
            }
        }
        for (int ks = 0; ks < 2; ++ks) {
            bf16x8 af[4], bfm[4];
            for (int mi = 0; mi < 4; ++mi)
                af[mi] = *(const bf16x8*)&As[(rowb + mi * 16 + ln) * 72 + ks * 32 + g * 8];
            for (int ni = 0; ni < 4; ++ni)
                bfm[ni] = *(const bf16x8*)&Bs[(colb + ni * 16 + ln) * 72 + ks * 32 + g * 8];
            for (int mi = 0; mi < 4; ++mi)
                for (int ni = 0; ni < 4; ++ni)
                    acc[mi][ni] = MFMA16(af[mi], bfm[ni], acc[mi][ni]);
        }
    }

    if (proj != 2) {
        for (int mi = 0; mi < 4; ++mi) {
            for (int ni = 0; ni < 4; ++ni) {
                int col = n0 + colb + ni * 16 + ln;
                float bv_ = bias[col];
                int rowbase = m0 + rowb + mi * 16 + g * 4;
                if (proj == 0) {
                    for (int r = 0; r < 4; ++r)
                        Qp[(size_t)(rowbase + r) * 1024 + col] =
                            (bf16)((acc[mi][ni][r] + bv_) * QSCALE);
                } else {
                    for (int r = 0; r < 4; ++r)
                        Kp[(size_t)(rowbase + r) * 1024 + col] =
                            (bf16)(acc[mi][ni][r] + bv_);
                }
            }
        }
    } else {
        __syncthreads();   // all waves done with As/Bs before Ts overwrite
        for (int mi = 0; mi < 4; ++mi) {
            for (int ni = 0; ni < 4; ++ni) {
                int col = colb + ni * 16 + ln;
                float bv_ = bias[n0 + col];
                int row = rowb + mi * 16 + g * 4;
                bf16x4 pk;
                for (int r = 0; r < 4; ++r) pk[r] = (bf16)(acc[mi][ni][r] + bv_);
                *(bf16x4*)&Ts[col * 132 + row] = pk;
            }
        }
        __syncthreads();
        const int bidx = m0 >> 11;
        const int tok0 = m0 & 2047;        // token offset WITHIN batch
        for (int i = 0; i < 8; ++i) {
            int c    = tid + 256 * i;
            int col  = c >> 4;
            int t64  = (c >> 3) & 1;
            int cc   = c & 7;
            int gcol = n0 + col;
            union { bf16 e[8]; uint4 u; } tmp;
            for (int j = 0; j < 8; ++j) {
                int s = 2 * cc + (j >> 2) + ((j & 3) << 4);
                tmp.e[j] = Ts[col * 132 + t64 * 64 + s];
            }
            size_t dst = ((size_t)(bidx * 16 + (gcol >> 6)) * 64 + (gcol & 63)) * 2048
                         + tok0 + t64 * 64 + cc * 8;
            *(uint4*)&Vt[dst] = tmp.u;
        }
    }
}

// ---------------------------------------------------------------------------
// Output projection: C[4096,1024] fp32 = Ctx(bf16) @ wo^T(bf16) + bo.
// 1-D grid 256, XCD swizzle (8 col-blocks of a row share an XCD).
// Same corrected pipeline as qkv_gemm.
// ---------------------------------------------------------------------------
__global__ __launch_bounds__(256) void gemm_out(
    const bf16* __restrict__ A, const bf16* __restrict__ B,
    const float* __restrict__ bias, float* __restrict__ C)
{
    __shared__ __align__(16) bf16 As[128 * 72];
    __shared__ __align__(16) bf16 Bs[128 * 72];

    const int id  = blockIdx.x;
    const int row = (id >> 6) * 8 + (id & 7);  // 0..31
    const int m0  = row * 128;
    const int n0  = ((id >> 3) & 7) * 128;

    const int tid  = threadIdx.x;
    const int lane = tid & 63;
    const int w    = tid >> 6;
    const int g    = lane >> 4;
    const int ln   = lane & 15;
    const int rowb = (w & 1) * 64;
    const int colb = (w >> 1) * 64;
    const int srow = tid >> 3, skc = (tid & 7) << 3;

    uint4 ra[4], rb[4];
    for (int i = 0; i < 4; ++i) {
        ra[i] = *(const uint4*)&A[(size_t)(m0 + srow + 32 * i) * 1024 + skc];
        rb[i] = *(const uint4*)&B[(size_t)(n0 + srow + 32 * i) * 1024 + skc];
    }

    f32x4 acc[4][4] = {};

    for (int k0 = 0; k0 < 1024; k0 += 64) {
        __syncthreads();
        for (int i = 0; i < 4; ++i) {
            *(uint4*)&As[(srow + 32 * i) * 72 + skc] = ra[i];
            *(uint4*)&Bs[(srow + 32 * i) * 72 + skc] = rb[i];
        }
        __syncthreads();
        if (k0 + 64 < 1024) {
            for (int i = 0; i < 4; ++i) {
                ra[i] = *(const uint4*)&A[(size_t)(m0 + srow + 32 * i) * 1024 + k0 + 64 + skc];
                rb[i] = *(const uint4*)&B[(size_t)(n0 + srow + 32 * i) * 1024 + k0 + 64 + skc];
            }
        }
        for (int ks = 0; ks < 2; ++ks) {
            bf16x8 af[4], bfm[4];
            for (int mi = 0; mi < 4; ++mi)
                af[mi] = *(const bf16x8*)&As[(rowb + mi * 16 + ln) * 72 + ks * 32 + g * 8];
            for (int ni = 0; ni < 4; ++ni)
                bfm[ni] = *(const bf16x8*)&Bs[(colb + ni * 16 + ln) * 72 + ks * 32 + g * 8];
            for (int mi = 0; mi < 4; ++mi)
                for (int ni = 0; ni < 4; ++ni)
                    acc[mi][ni] = MFMA16(af[mi], bfm[ni], acc[mi][ni]);
        }
    }

    for (int mi = 0; mi < 4; ++mi) {
        for (int ni = 0; ni < 4; ++ni) {
            int col = n0 + colb + ni * 16 + ln;
            float bv_ = bias[col];
            int rowbase = m0 + rowb + mi * 16 + g * 4;
            for (int r = 0; r < 4; ++r)
                C[(size_t)(rowbase + r) * 1024 + col] = acc[mi][ni][r] + bv_;
        }
    }
}

// ---------------------------------------------------------------------------
// Flash attention (no-max softmax; logits pre-scaled by 0.125*log2e -> exp2).
// 1-D grid 512, XCD swizzle: the 16 q-tiles of one (b,h) share id%8 -> same
// XCD -> K/V served from one L2. Corrected pipeline: K/V loads for t+1 issue
// AFTER the post-store barrier, in flight during QK^T/softmax/PV.
// V pre-permuted (kv' = (s&15)*4 + (s>>4)); P packed b64 xor-swizzled.
// LDS 36864 B -> 4 blocks/CU; Ps aliases Q staging.
// ---------------------------------------------------------------------------
__global__ __launch_bounds__(256) void attn_kernel(
    const bf16* __restrict__ Qp, const bf16* __restrict__ Kp,
    const bf16* __restrict__ Vt, bf16* __restrict__ Ctx)
{
    __shared__ __align__(16) bf16 smem[9216 + 4608 + 4608];
    bf16* Ps = smem;               // [128][64] swizzled
    bf16* Qs = smem;               // [128][72] staging only (aliased)
    bf16* Ks = smem + 9216;        // [64][72]  [kv][d]
    bf16* Vs = Ks + 4608;          // [64][72]  [d][kv']

    const int id = blockIdx.x;
    const int qt = (id >> 3) & 15;
    const int bh = (id >> 7) * 8 + (id & 7);   // 0..31

    const int tid  = threadIdx.x;
    const int lane = tid & 63;
    const int w    = tid >> 6;
    const int g    = lane >> 4;
    const int ln   = lane & 15;
    const size_t rowQ0 = (size_t)(bh >> 4) * 2048 + qt * 128;
    const size_t rowK0 = (size_t)(bh >> 4) * 2048;
    const int hcol = (bh & 15) * 64;
    const bf16* VtB = Vt + (size_t)bh * 64 * 2048;

    // stage Q tile 128x64 and preload A-frags
    for (int i = 0; i < 4; ++i) {
        int c = tid + 256 * i;
        int row = c >> 3, dc = (c & 7) << 3;
        *(uint4*)&Qs[row * 72 + dc] =
            *(const uint4*)&Qp[(rowQ0 + row) * 1024 + hcol + dc];
    }
    __syncthreads();
    bf16x8 qf[2][2];
    for (int mi = 0; mi < 2; ++mi)
        for (int ks = 0; ks < 2; ++ks)
            qf[mi][ks] = *(const bf16x8*)&Qs[(w * 32 + mi * 16 + ln) * 72 + ks * 32 + g * 8];

    f32x4 oacc[2][4] = {};
    float l_part[2][4] = {};

    const int sr = tid >> 3, sdc = (tid & 7) << 3;
    uint4 rk[2], rv[2];
    for (int i = 0; i < 2; ++i) {
        rk[i] = *(const uint4*)&Kp[(rowK0 + sr + 32 * i) * 1024 + hcol + sdc];
        rv[i] = *(const uint4*)&VtB[(size_t)(sr + 32 * i) * 2048 + sdc];
    }

    for (int t = 0; t < 32; ++t) {
        __syncthreads();   // prev tile consumed (t=0: qf preload done in all waves)
        for (int i = 0; i < 2; ++i) {
            *(uint4*)&Ks[(sr + 32 * i) * 72 + sdc] = rk[i];
            *(uint4*)&Vs[(sr + 32 * i) * 72 + sdc] = rv[i];
        }
        __syncthreads();
        if (t < 31) {      // in flight during QK^T / softmax / PV below
            for (int i = 0; i < 2; ++i) {
                rk[i] = *(const uint4*)&Kp[(rowK0 + (t + 1) * 64 + sr + 32 * i) * 1024 + hcol + sdc];
                rv[i] = *(const uint4*)&VtB[(size_t)(sr + 32 * i) * 2048 + (t + 1) * 64 + sdc];
            }
        }

        // S = Q K^T (pre-scaled)
        f32x4 sf[2][4] = {};
        for (int ks = 0; ks < 2; ++ks) {
            bf16x8 kf[4];
            for (int nj = 0; nj < 4; ++nj)
                kf[nj] = *(const bf16x8*)&Ks[(nj * 16 + ln) * 72 + ks * 32 + g * 8];
            for (int mi = 0; mi < 2; ++mi)
                for (int nj = 0; nj < 4; ++nj)
                    sf[mi][nj] = MFMA16(qf[mi][ks], kf[nj], sf[mi][nj]);
        }

        // P = exp2(S), packed b64 store (wave-private rows, no barrier needed)
        for (int mi = 0; mi < 2; ++mi) {
            for (int r = 0; r < 4; ++r) {
                float p0 = __builtin_amdgcn_exp2f(sf[mi][0][r]);
                float p1 = __builtin_amdgcn_exp2f(sf[mi][1][r]);
                float p2 = __builtin_amdgcn_exp2f(sf[mi][2][r]);
                float p3 = __builtin_amdgcn_exp2f(sf[mi][3][r]);
                l_part[mi][r] += (p0 + p1) + (p2 + p3);
                int qrow = w * 32 + mi * 16 + g * 4 + r;
                int slot = ln ^ ((qrow & 7) << 1);
                bf16x4 pk;
                pk[0] = (bf16)p0; pk[1] = (bf16)p1; pk[2] = (bf16)p2; pk[3] = (bf16)p3;
                *(bf16x4*)&Ps[qrow * 64 + slot * 4] = pk;
            }
        }

        // O += P V
        for (int ks = 0; ks < 2; ++ks) {
            bf16x8 pf[2], vf[4];
            for (int mi = 0; mi < 2; ++mi) {
                int row = w * 32 + mi * 16 + ln;
                int p = (ks * 8 + g * 2) ^ ((row & 7) << 1);
                pf[mi] = *(const bf16x8*)&Ps[row * 64 + p * 4];
            }
            for (int nd = 0; nd < 4; ++nd)
                vf[nd] = *(const bf16x8*)&Vs[(nd * 16 + ln) * 72 + ks * 32 + g * 8];
            for (int mi = 0; mi < 2; ++mi)
                for (int nd = 0; nd < 4; ++nd)
                    oacc[mi][nd] = MFMA16(pf[mi], vf[nd], oacc[mi][nd]);
        }
    }

    // epilogue: row-sum reduction (16-lane groups), normalize, store
    for (int mi = 0; mi < 2; ++mi) {
        for (int r = 0; r < 4; ++r) {
            float l = l_part[mi][r];
            for (int off = 8; off >= 1; off >>= 1)
                l += __shfl_xor(l, off, 64);
            float inv = 1.0f / l;
            size_t row = rowQ0 + w * 32 + mi * 16 + g * 4 + r;
            for (int nd = 0; nd < 4; ++nd)
                Ctx[row * 1024 + hcol + nd * 16 + ln] = (bf16)(oacc[mi][nd][r] * inv);
        }
    }
}

extern "C" void kernel_launch(void* const* d_in, const int* in_sizes, int n_in,
                              void* d_out, int out_size, void* d_ws, size_t ws_size,
                              hipStream_t stream)
{
    const float* q  = (const float*)d_in[0];
    const float* k  = (const float*)d_in[1];
    const float* v  = (const float*)d_in[2];
    const float* wq = (const float*)d_in[3];
    const float* bq = (const float*)d_in[4];
    const float* wk = (const float*)d_in[5];
    const float* bk = (const float*)d_in[6];
    const float* wv = (const float*)d_in[7];
    const float* bv = (const float*)d_in[8];
    const float* wo = (const float*)d_in[9];
    const float* bo = (const float*)d_in[10];
    float* out = (float*)d_out;

    const int M = 4096, D = 1024;
    bf16* Qp = (bf16*)d_ws;                 // 8 MB
    bf16* Kp = Qp + (size_t)M * D;          // 8 MB
    bf16* Vt = Kp + (size_t)M * D;          // 8 MB, [bh][d][tok' (kv'-permuted)]
    bf16* Ctx = Qp;    // alias: each attn block overwrites only its consumed Q rows
    bf16* wob = Kp;    // Kp dead after attn -> holds bf16 wo for gemm_out

    // bf16 weight scratch in d_out (fully overwritten by gemm_out afterwards)
    bf16* wqb = (bf16*)d_out;               // 2 MB
    bf16* wkb = wqb + (size_t)D * D;
    bf16* wvb = wkb + (size_t)D * D;

    cvt3_kernel<<<dim3(512, 3), 256, 0, stream>>>(wq, wqb, wk, wkb, wv, wvb);
    qkv_gemm<<<768, 256, 0, stream>>>(q, k, v, wqb, bq, wkb, bk, wvb, bv,
                                      Qp, Kp, Vt);
    attn_kernel<<<512, 256, 0, stream>>>(Qp, Kp, Vt, Ctx);
    cvt_kernel<<<512, 256, 0, stream>>>(wo, wob, D * D);   // into dead Kp
    gemm_out<<<256, 256, 0, stream>>>(Ctx, wob, bo, out);
}

// Round 7
// 238.974 us; speedup vs baseline: 1.5914x; 1.4918x over previous
//
#include <hip/hip_runtime.h>

typedef __bf16 bf16;
typedef __bf16 bf16x4 __attribute__((ext_vector_type(4)));
typedef __bf16 bf16x8 __attribute__((ext_vector_type(8)));
typedef float f32x4 __attribute__((ext_vector_type(4)));

#define MFMA16(a, b, c) __builtin_amdgcn_mfma_f32_16x16x32_bf16((a), (b), (c), 0, 0, 0)

// 0.125 (attn scale) * log2(e): folded into Q projection so softmax is exp2(s).
#define QSCALE 0.18033688011112042f

// async global->LDS, 16 B per lane. LDS dest = wave-uniform base + lane*16.
__device__ inline void gld16(const void* g, void* l) {
    __builtin_amdgcn_global_load_lds(
        (const __attribute__((address_space(1))) unsigned int*)g,
        (__attribute__((address_space(3))) unsigned int*)l, 16, 0, 0);
}

__device__ inline bf16x8 cvt8(float4 a, float4 b) {
    bf16x8 v;
    v[0] = (bf16)a.x; v[1] = (bf16)a.y; v[2] = (bf16)a.z; v[3] = (bf16)a.w;
    v[4] = (bf16)b.x; v[5] = (bf16)b.y; v[6] = (bf16)b.z; v[7] = (bf16)b.w;
    return v;
}

// ---------------------------------------------------------------------------
// fp32 -> bf16: 3 weight matrices in one dispatch.
// ---------------------------------------------------------------------------
__global__ __launch_bounds__(256) void cvt3_kernel(
    const float* __restrict__ s0, bf16* __restrict__ d0,
    const float* __restrict__ s1, bf16* __restrict__ d1,
    const float* __restrict__ s2, bf16* __restrict__ d2)
{
    const float* src = blockIdx.y == 0 ? s0 : blockIdx.y == 1 ? s1 : s2;
    bf16*        dst = blockIdx.y == 0 ? d0 : blockIdx.y == 1 ? d1 : d2;
    int i = (blockIdx.x * 256 + threadIdx.x) * 8;
    float4 a = *(const float4*)&src[i];
    float4 b = *(const float4*)&src[i + 4];
    *(bf16x8*)&dst[i] = cvt8(a, b);
}

__global__ __launch_bounds__(256) void cvt_kernel(
    const float* __restrict__ src, bf16* __restrict__ dst, int n)
{
    int i = (blockIdx.x * 256 + threadIdx.x) * 8;
    if (i < n) {
        float4 a = *(const float4*)&src[i];
        float4 b = *(const float4*)&src[i + 4];
        *(bf16x8*)&dst[i] = cvt8(a, b);
    }
}

// ---------------------------------------------------------------------------
// Fused QKV projection, grid 768 (XCD-swizzled: 8 col-blocks of one
// (proj,row-slab) share id%8 -> same XCD L2 serves the A-slab re-reads).
// LDS layout: unpadded [row][64] with chunk-xor swizzle
// (phys_chunk = logical_chunk ^ (row&7)) -> conflict-free b128 reads AND the
// contiguous wave-writes global_load_lds requires.
// B (bf16): double-buffered global_load_lds, issued after the LDS-visibility
// barrier -> in flight across the whole MFMA phase. A (fp32): register
// prefetch + cvt + ds_write (same flight window).
// ---------------------------------------------------------------------------
__global__ __launch_bounds__(256) void qkv_gemm(
    const float* __restrict__ q, const float* __restrict__ k,
    const float* __restrict__ v,
    const bf16* __restrict__ wq, const float* __restrict__ bq,
    const bf16* __restrict__ wk, const float* __restrict__ bk,
    const bf16* __restrict__ wv, const float* __restrict__ bv,
    bf16* __restrict__ Qp, bf16* __restrict__ Kp, bf16* __restrict__ Vt)
{
    __shared__ __align__(16) bf16 sm[8192 + 2 * 8192];  // As | Bs(x2); Ts alias
    bf16* As = sm;             // [128][64] swizzled
    bf16* Bs = sm + 8192;      // 2 x [128][64] swizzled
    bf16* Ts = sm;             // epilogue transpose [128][132]

    const int id  = blockIdx.x;
    const int pr  = (id >> 6) * 8 + (id & 7);        // proj*32+row, 0..95
    const int proj = pr >> 5;
    const int m0  = (pr & 31) * 128;
    const int n0  = ((id >> 3) & 7) * 128;

    const float* A    = proj == 0 ? q  : proj == 1 ? k  : v;
    const bf16*  B    = proj == 0 ? wq : proj == 1 ? wk : wv;
    const float* bias = proj == 0 ? bq : proj == 1 ? bk : bv;

    const int tid  = threadIdx.x;
    const int lane = tid & 63;
    const int w    = tid >> 6;
    const int g    = lane >> 4;
    const int ln   = lane & 15;
    const int rowb = (w & 1) * 64;
    const int colb = (w >> 1) * 64;
    const int srow = tid >> 3, slc = tid & 7;        // A-staging coords
    const int ro   = lane >> 3, lc = lane & 7;       // glb_lds lane coords

    // preload A(0) regs; issue B(0) -> buf0
    float4 ra[4][2];
    for (int i = 0; i < 4; ++i) {
        const float* p = &A[(size_t)(m0 + srow + 32 * i) * 1024 + slc * 8];
        ra[i][0] = *(const float4*)p;
        ra[i][1] = *(const float4*)(p + 4);
    }
    for (int j = 0; j < 4; ++j) {
        int base = w * 32 + j * 8;
        int row  = base + ro;
        int c    = lc ^ (row & 7);
        gld16(&B[(size_t)(n0 + row) * 1024 + c * 8], &Bs[base * 64]);
    }

    f32x4 acc[4][4] = {};

    for (int t = 0; t < 16; ++t) {
        __syncthreads();                     // drains B(t); As safe to rewrite
        for (int i = 0; i < 4; ++i) {
            int row = srow + 32 * i;
            *(bf16x8*)&As[row * 64 + (slc ^ (row & 7)) * 8] = cvt8(ra[i][0], ra[i][1]);
        }
        __syncthreads();                     // As visible (nothing vmem in flight)
        if (t < 15) {                        // t+1 loads fly through MFMA below
            int k1 = (t + 1) * 64;
            for (int i = 0; i < 4; ++i) {
                const float* p = &A[(size_t)(m0 + srow + 32 * i) * 1024 + k1 + slc * 8];
                ra[i][0] = *(const float4*)p;
                ra[i][1] = *(const float4*)(p + 4);
            }
            int bsel = (t + 1) & 1;
            for (int j = 0; j < 4; ++j) {
                int base = w * 32 + j * 8;
                int row  = base + ro;
                int c    = lc ^ (row & 7);
                gld16(&B[(size_t)(n0 + row) * 1024 + k1 + c * 8],
                      &Bs[bsel * 8192 + base * 64]);
            }
        }
        const bf16* Bt = Bs + (t & 1) * 8192;
        for (int ks = 0; ks < 2; ++ks) {
            bf16x8 af[4], bfm[4];
            for (int mi = 0; mi < 4; ++mi) {
                int row = rowb + mi * 16 + ln;
                af[mi] = *(const bf16x8*)&As[row * 64 + ((ks * 4 + g) ^ (ln & 7)) * 8];
            }
            for (int ni = 0; ni < 4; ++ni) {
                int row = colb + ni * 16 + ln;
                bfm[ni] = *(const bf16x8*)&Bt[row * 64 + ((ks * 4 + g) ^ (ln & 7)) * 8];
            }
            for (int mi = 0; mi < 4; ++mi)
                for (int ni = 0; ni < 4; ++ni)
                    acc[mi][ni] = MFMA16(af[mi], bfm[ni], acc[mi][ni]);
        }
    }

    if (proj != 2) {
        for (int mi = 0; mi < 4; ++mi) {
            for (int ni = 0; ni < 4; ++ni) {
                int col = n0 + colb + ni * 16 + ln;
                float bv_ = bias[col];
                int rowbase = m0 + rowb + mi * 16 + g * 4;
                if (proj == 0) {
                    for (int r = 0; r < 4; ++r)
                        Qp[(size_t)(rowbase + r) * 1024 + col] =
                            (bf16)((acc[mi][ni][r] + bv_) * QSCALE);
                } else {
                    for (int r = 0; r < 4; ++r)
                        Kp[(size_t)(rowbase + r) * 1024 + col] =
                            (bf16)(acc[mi][ni][r] + bv_);
                }
            }
        }
    } else {
        __syncthreads();   // all waves done with As/Bs before Ts overwrite
        for (int mi = 0; mi < 4; ++mi) {
            for (int ni = 0; ni < 4; ++ni) {
                int col = colb + ni * 16 + ln;
                float bv_ = bias[n0 + col];
                int row = rowb + mi * 16 + g * 4;
                bf16x4 pk;
                for (int r = 0; r < 4; ++r) pk[r] = (bf16)(acc[mi][ni][r] + bv_);
                *(bf16x4*)&Ts[col * 132 + row] = pk;
            }
        }
        __syncthreads();
        const int bidx = m0 >> 11;
        const int tok0 = m0 & 2047;        // token offset WITHIN batch
        for (int i = 0; i < 8; ++i) {
            int c    = tid + 256 * i;
            int col  = c >> 4;
            int t64  = (c >> 3) & 1;
            int cc   = c & 7;
            int gcol = n0 + col;
            union { bf16 e[8]; uint4 u; } tmp;
            for (int j = 0; j < 8; ++j) {
                int s = 2 * cc + (j >> 2) + ((j & 3) << 4);
                tmp.e[j] = Ts[col * 132 + t64 * 64 + s];
            }
            size_t dst = ((size_t)(bidx * 16 + (gcol >> 6)) * 64 + (gcol & 63)) * 2048
                         + tok0 + t64 * 64 + cc * 8;
            *(uint4*)&Vt[dst] = tmp.u;
        }
    }
}

// ---------------------------------------------------------------------------
// Output projection: C[4096,1024] fp32 = Ctx(bf16) @ wo^T(bf16) + bo.
// 64x128 tiles -> grid 512 (2/CU). Both operands double-buffered via
// global_load_lds; ONE barrier per K-iter.
// ---------------------------------------------------------------------------
__global__ __launch_bounds__(256) void gemm_out(
    const bf16* __restrict__ A, const bf16* __restrict__ B,
    const float* __restrict__ bias, float* __restrict__ C)
{
    __shared__ __align__(16) bf16 sm[2 * 4096 + 2 * 8192];
    bf16* As = sm;             // 2 x [64][64] swizzled
    bf16* Bs = sm + 8192;      // 2 x [128][64] swizzled

    const int id = blockIdx.x;
    const int m0 = ((id >> 6) * 8 + (id & 7)) * 64;   // rows 0..63 -> m0
    const int n0 = ((id >> 3) & 7) * 128;

    const int tid  = threadIdx.x;
    const int lane = tid & 63;
    const int w    = tid >> 6;
    const int g    = lane >> 4;
    const int ln   = lane & 15;
    const int rowb = (w & 1) * 32;
    const int colb = (w >> 1) * 64;
    const int ro   = lane >> 3, lc = lane & 7;

    // issue tile t into buf[t&1]
    auto issue = [&](int t) {
        int k0 = t * 64, sel = t & 1;
        for (int j = 0; j < 2; ++j) {
            int base = w * 16 + j * 8;
            int row  = base + ro;
            int c    = lc ^ (row & 7);
            gld16(&A[(size_t)(m0 + row) * 1024 + k0 + c * 8],
                  &As[sel * 4096 + base * 64]);
        }
        for (int j = 0; j < 4; ++j) {
            int base = w * 32 + j * 8;
            int row  = base + ro;
            int c    = lc ^ (row & 7);
            gld16(&B[(size_t)(n0 + row) * 1024 + k0 + c * 8],
                  &Bs[sel * 8192 + base * 64]);
        }
    };

    issue(0);
    f32x4 acc[2][4] = {};

    for (int t = 0; t < 16; ++t) {
        __syncthreads();                 // drains tile t; buf^1 free (readers done)
        if (t < 15) issue(t + 1);        // flies through MFMA below
        const bf16* At = As + (t & 1) * 4096;
        const bf16* Bt = Bs + (t & 1) * 8192;
        for (int ks = 0; ks < 2; ++ks) {
            bf16x8 af[2], bfm[4];
            for (int mi = 0; mi < 2; ++mi) {
                int row = rowb + mi * 16 + ln;
                af[mi] = *(const bf16x8*)&At[row * 64 + ((ks * 4 + g) ^ (ln & 7)) * 8];
            }
            for (int ni = 0; ni < 4; ++ni) {
                int row = colb + ni * 16 + ln;
                bfm[ni] = *(const bf16x8*)&Bt[row * 64 + ((ks * 4 + g) ^ (ln & 7)) * 8];
            }
            for (int mi = 0; mi < 2; ++mi)
                for (int ni = 0; ni < 4; ++ni)
                    acc[mi][ni] = MFMA16(af[mi], bfm[ni], acc[mi][ni]);
        }
    }

    for (int mi = 0; mi < 2; ++mi) {
        for (int ni = 0; ni < 4; ++ni) {
            int col = n0 + colb + ni * 16 + ln;
            float bv_ = bias[col];
            int rowbase = m0 + rowb + mi * 16 + g * 4;
            for (int r = 0; r < 4; ++r)
                C[(size_t)(rowbase + r) * 1024 + col] = acc[mi][ni][r] + bv_;
        }
    }
}

// ---------------------------------------------------------------------------
// Flash attention (no-max softmax, logits pre-scaled by 0.125*log2e -> exp2).
// Grid 512, XCD-swizzled (16 q-tiles of one (b,h) share an XCD L2 for KV).
// K/V double-buffered via global_load_lds (swizzled unpadded [64][64]);
// ONE barrier per KV tile; t+1 loads fly through QK/softmax/PV of tile t.
// V pre-permuted (kv' = (s&15)*4+(s>>4)); P packed b64 xor-swizzled in LDS.
// LDS 48 KiB; Ps aliases Q staging (Q is register-resident after preload).
// ---------------------------------------------------------------------------
__global__ __launch_bounds__(256) void attn_kernel(
    const bf16* __restrict__ Qp, const bf16* __restrict__ Kp,
    const bf16* __restrict__ Vt, bf16* __restrict__ Ctx)
{
    __shared__ __align__(16) bf16 smem[8192 + 2 * 4096 + 2 * 4096];
    bf16* Ps = smem;               // [128][64] swizzled slots
    bf16* Qs = smem;               // [128][64] swizzled staging (aliased)
    bf16* Ks = smem + 8192;        // 2 x [64][64] swizzled  [kv][d]
    bf16* Vs = smem + 16384;       // 2 x [64][64] swizzled  [d][kv']

    const int id = blockIdx.x;
    const int qt = (id >> 3) & 15;
    const int bh = (id >> 7) * 8 + (id & 7);

    const int tid  = threadIdx.x;
    const int lane = tid & 63;
    const int w    = tid >> 6;
    const int g    = lane >> 4;
    const int ln   = lane & 15;
    const int ro   = lane >> 3, lc = lane & 7;
    const size_t rowQ0 = (size_t)(bh >> 4) * 2048 + qt * 128;
    const size_t rowK0 = (size_t)(bh >> 4) * 2048;
    const int hcol = (bh & 15) * 64;
    const bf16* VtB = Vt + (size_t)bh * 64 * 2048;

    // stage Q (wave-private rows) and K/V tile 0
    for (int j = 0; j < 4; ++j) {
        int base = w * 32 + j * 8;
        int row  = base + ro;
        int c    = lc ^ (row & 7);
        gld16(&Qp[(rowQ0 + row) * 1024 + hcol + c * 8], &Qs[base * 64]);
    }
    for (int j = 0; j < 2; ++j) {
        int base = w * 16 + j * 8;
        int kv   = base + ro;
        int c    = lc ^ (kv & 7);
        gld16(&Kp[(rowK0 + kv) * 1024 + hcol + c * 8], &Ks[base * 64]);
        gld16(&VtB[(size_t)kv * 2048 + c * 8], &Vs[base * 64]);
    }
    __syncthreads();

    bf16x8 qf[2][2];
    for (int mi = 0; mi < 2; ++mi)
        for (int ks = 0; ks < 2; ++ks) {
            int row = w * 32 + mi * 16 + ln;
            qf[mi][ks] = *(const bf16x8*)&Qs[row * 64 + ((ks * 4 + g) ^ (ln & 7)) * 8];
        }

    f32x4 oacc[2][4] = {};
    float l_part[2][4] = {};

    for (int t = 0; t < 32; ++t) {
        if (t < 31) {                   // t+1 KV flies through this tile's compute
            int sel = (t + 1) & 1, kvo = (t + 1) * 64;
            for (int j = 0; j < 2; ++j) {
                int base = w * 16 + j * 8;
                int kv   = base + ro;
                int c    = lc ^ (kv & 7);
                gld16(&Kp[(rowK0 + kvo + kv) * 1024 + hcol + c * 8],
                      &Ks[sel * 4096 + base * 64]);
                gld16(&VtB[(size_t)kv * 2048 + kvo + c * 8],
                      &Vs[sel * 4096 + base * 64]);
            }
        }
        const bf16* Kt = Ks + (t & 1) * 4096;
        const bf16* Vti = Vs + (t & 1) * 4096;

        // S = Q K^T (pre-scaled)
        f32x4 sf[2][4] = {};
        for (int ks = 0; ks < 2; ++ks) {
            bf16x8 kf[4];
            for (int nj = 0; nj < 4; ++nj) {
                int row = nj * 16 + ln;
                kf[nj] = *(const bf16x8*)&Kt[row * 64 + ((ks * 4 + g) ^ (ln & 7)) * 8];
            }
            for (int mi = 0; mi < 2; ++mi)
                for (int nj = 0; nj < 4; ++nj)
                    sf[mi][nj] = MFMA16(qf[mi][ks], kf[nj], sf[mi][nj]);
        }

        // P = exp2(S), packed b64 store (wave-private rows)
        for (int mi = 0; mi < 2; ++mi) {
            for (int r = 0; r < 4; ++r) {
                float p0 = __builtin_amdgcn_exp2f(sf[mi][0][r]);
                float p1 = __builtin_amdgcn_exp2f(sf[mi][1][r]);
                float p2 = __builtin_amdgcn_exp2f(sf[mi][2][r]);
                float p3 = __builtin_amdgcn_exp2f(sf[mi][3][r]);
                l_part[mi][r] += (p0 + p1) + (p2 + p3);
                int qrow = w * 32 + mi * 16 + g * 4 + r;
                int slot = ln ^ ((qrow & 7) << 1);
                bf16x4 pk;
                pk[0] = (bf16)p0; pk[1] = (bf16)p1; pk[2] = (bf16)p2; pk[3] = (bf16)p3;
                *(bf16x4*)&Ps[qrow * 64 + slot * 4] = pk;
            }
        }

        // O += P V
        for (int ks = 0; ks < 2; ++ks) {
            bf16x8 pf[2], vf[4];
            for (int mi = 0; mi < 2; ++mi) {
                int row = w * 32 + mi * 16 + ln;
                int p = (ks * 8 + g * 2) ^ ((row & 7) << 1);
                pf[mi] = *(const bf16x8*)&Ps[row * 64 + p * 4];
            }
            for (int nd = 0; nd < 4; ++nd) {
                int row = nd * 16 + ln;
                vf[nd] = *(const bf16x8*)&Vti[row * 64 + ((ks * 4 + g) ^ (ln & 7)) * 8];
            }
            for (int mi = 0; mi < 2; ++mi)
                for (int nd = 0; nd < 4; ++nd)
                    oacc[mi][nd] = MFMA16(pf[mi], vf[nd], oacc[mi][nd]);
        }
        __syncthreads();   // drains t+1 KV loads; buf swap safe
    }

    // epilogue: row-sum reduction (16-lane groups), normalize, store
    for (int mi = 0; mi < 2; ++mi) {
        for (int r = 0; r < 4; ++r) {
            float l = l_part[mi][r];
            for (int off = 8; off >= 1; off >>= 1)
                l += __shfl_xor(l, off, 64);
            float inv = 1.0f / l;
            size_t row = rowQ0 + w * 32 + mi * 16 + g * 4 + r;
            for (int nd = 0; nd < 4; ++nd)
                Ctx[row * 1024 + hcol + nd * 16 + ln] = (bf16)(oacc[mi][nd][r] * inv);
        }
    }
}

extern "C" void kernel_launch(void* const* d_in, const int* in_sizes, int n_in,
                              void* d_out, int out_size, void* d_ws, size_t ws_size,
                              hipStream_t stream)
{
    const float* q  = (const float*)d_in[0];
    const float* k  = (const float*)d_in[1];
    const float* v  = (const float*)d_in[2];
    const float* wq = (const float*)d_in[3];
    const float* bq = (const float*)d_in[4];
    const float* wk = (const float*)d_in[5];
    const float* bk = (const float*)d_in[6];
    const float* wv = (const float*)d_in[7];
    const float* bv = (const float*)d_in[8];
    const float* wo = (const float*)d_in[9];
    const float* bo = (const float*)d_in[10];
    float* out = (float*)d_out;

    const int M = 4096, D = 1024;
    bf16* Qp = (bf16*)d_ws;                 // 8 MB
    bf16* Kp = Qp + (size_t)M * D;          // 8 MB
    bf16* Vt = Kp + (size_t)M * D;          // 8 MB, [bh][d][tok' (kv'-permuted)]
    bf16* Ctx = Qp;    // alias: each attn block overwrites only its consumed Q rows
    bf16* wob = Kp;    // Kp dead after attn -> holds bf16 wo for gemm_out

    // bf16 weight scratch in d_out (fully overwritten by gemm_out afterwards)
    bf16* wqb = (bf16*)d_out;               // 2 MB
    bf16* wkb = wqb + (size_t)D * D;
    bf16* wvb = wkb + (size_t)D * D;

    cvt3_kernel<<<dim3(512, 3), 256, 0, stream>>>(wq, wqb, wk, wkb, wv, wvb);
    qkv_gemm<<<768, 256, 0, stream>>>(q, k, v, wqb, bq, wkb, bk, wvb, bv,
                                      Qp, Kp, Vt);
    attn_kernel<<<512, 256, 0, stream>>>(Qp, Kp, Vt, Ctx);
    cvt_kernel<<<512, 256, 0, stream>>>(wo, wob, D * D);   // into dead Kp
    gemm_out<<<512, 256, 0, stream>>>(Ctx, wob, bo, out);
}

// Round 8
// 224.195 us; speedup vs baseline: 1.6963x; 1.0659x over previous
//
#include <hip/hip_runtime.h>

typedef __bf16 bf16;
typedef __bf16 bf16x4 __attribute__((ext_vector_type(4)));
typedef __bf16 bf16x8 __attribute__((ext_vector_type(8)));
typedef float f32x4 __attribute__((ext_vector_type(4)));

#define MFMA16(a, b, c) __builtin_amdgcn_mfma_f32_16x16x32_bf16((a), (b), (c), 0, 0, 0)

// 0.125 (attn scale) * log2(e): folded into Q projection so softmax is exp2(s).
#define QSCALE 0.18033688011112042f

// async global->LDS, 16 B per lane. LDS dest = wave-uniform base + lane*16.
__device__ inline void gld16(const void* g, void* l) {
    __builtin_amdgcn_global_load_lds(
        (const __attribute__((address_space(1))) unsigned int*)g,
        (__attribute__((address_space(3))) unsigned int*)l, 16, 0, 0);
}

__device__ inline bf16x8 cvt8(float4 a, float4 b) {
    bf16x8 v;
    v[0] = (bf16)a.x; v[1] = (bf16)a.y; v[2] = (bf16)a.z; v[3] = (bf16)a.w;
    v[4] = (bf16)b.x; v[5] = (bf16)b.y; v[6] = (bf16)b.z; v[7] = (bf16)b.w;
    return v;
}

// ---------------------------------------------------------------------------
// fp32 -> bf16, 7 tensors in one dispatch: q,k,v (4M elems) + 4 weights (1M).
// ---------------------------------------------------------------------------
__global__ __launch_bounds__(256) void cvt7_kernel(
    const float* __restrict__ q,  bf16* __restrict__ qb,
    const float* __restrict__ k,  bf16* __restrict__ kb,
    const float* __restrict__ v,  bf16* __restrict__ vb,
    const float* __restrict__ wq, bf16* __restrict__ wqb,
    const float* __restrict__ wk, bf16* __restrict__ wkb,
    const float* __restrict__ wv, bf16* __restrict__ wvb,
    const float* __restrict__ wo, bf16* __restrict__ wob)
{
    const float* src; bf16* dst; int n;
    switch (blockIdx.y) {
        case 0: src = q;  dst = qb;  n = 1 << 22; break;
        case 1: src = k;  dst = kb;  n = 1 << 22; break;
        case 2: src = v;  dst = vb;  n = 1 << 22; break;
        case 3: src = wq; dst = wqb; n = 1 << 20; break;
        case 4: src = wk; dst = wkb; n = 1 << 20; break;
        case 5: src = wv; dst = wvb; n = 1 << 20; break;
        default: src = wo; dst = wob; n = 1 << 20; break;
    }
    int i = (blockIdx.x * 256 + threadIdx.x) * 8;
    if (i < n) {
        float4 a = *(const float4*)&src[i];
        float4 b = *(const float4*)&src[i + 4];
        *(bf16x8*)&dst[i] = cvt8(a, b);
    }
}

__global__ __launch_bounds__(256) void cvt3_kernel(
    const float* __restrict__ s0, bf16* __restrict__ d0,
    const float* __restrict__ s1, bf16* __restrict__ d1,
    const float* __restrict__ s2, bf16* __restrict__ d2)
{
    const float* src = blockIdx.y == 0 ? s0 : blockIdx.y == 1 ? s1 : s2;
    bf16*        dst = blockIdx.y == 0 ? d0 : blockIdx.y == 1 ? d1 : d2;
    int i = (blockIdx.x * 256 + threadIdx.x) * 8;
    float4 a = *(const float4*)&src[i];
    float4 b = *(const float4*)&src[i + 4];
    *(bf16x8*)&dst[i] = cvt8(a, b);
}

__global__ __launch_bounds__(256) void cvt_kernel(
    const float* __restrict__ src, bf16* __restrict__ dst, int n)
{
    int i = (blockIdx.x * 256 + threadIdx.x) * 8;
    if (i < n) {
        float4 a = *(const float4*)&src[i];
        float4 b = *(const float4*)&src[i + 4];
        *(bf16x8*)&dst[i] = cvt8(a, b);
    }
}

// ---------------------------------------------------------------------------
// Pure-bf16 fused QKV projection (fast path), m97-form: both operands staged
// with global_load_lds into single-buffered swizzled LDS, 2 barriers/iter;
// latency hidden by 3 blocks/CU cross-block overlap. Grid 768 XCD-swizzled.
// proj0 -> Qp (scaled), proj1 -> Kp, proj2 -> Vt[bh][d][t64*64+kv'],
// kv' = (s&15)*4 + (s>>4), via LDS transpose.
// ---------------------------------------------------------------------------
__global__ __launch_bounds__(256) void qkv_bf16(
    const bf16* __restrict__ qb, const bf16* __restrict__ kb,
    const bf16* __restrict__ vb,
    const bf16* __restrict__ wq, const float* __restrict__ bq,
    const bf16* __restrict__ wk, const float* __restrict__ bk,
    const bf16* __restrict__ wv, const float* __restrict__ bv,
    bf16* __restrict__ Qp, bf16* __restrict__ Kp, bf16* __restrict__ Vt)
{
    __shared__ __align__(16) bf16 sm[16896];   // As(8192)+Bs(8192); Ts alias 16896
    bf16* As = sm;
    bf16* Bs = sm + 8192;
    bf16* Ts = sm;                             // epilogue transpose [128][132]

    const int id  = blockIdx.x;
    const int pr  = (id >> 6) * 8 + (id & 7);  // proj*32+row, 0..95
    const int proj = pr >> 5;
    const int m0  = (pr & 31) * 128;
    const int n0  = ((id >> 3) & 7) * 128;

    const bf16*  A    = proj == 0 ? qb : proj == 1 ? kb : vb;
    const bf16*  B    = proj == 0 ? wq : proj == 1 ? wk : wv;
    const float* bias = proj == 0 ? bq : proj == 1 ? bk : bv;

    const int tid  = threadIdx.x;
    const int lane = tid & 63;
    const int w    = tid >> 6;
    const int g    = lane >> 4;
    const int ln   = lane & 15;
    const int rowb = (w & 1) * 64;
    const int colb = (w >> 1) * 64;
    const int ro   = lane >> 3, lc = lane & 7;

    auto issue = [&](int t) {
        int k0 = t * 64;
        for (int j = 0; j < 4; ++j) {
            int base = w * 32 + j * 8;
            int row  = base + ro;
            int c    = lc ^ (row & 7);
            gld16(&A[(size_t)(m0 + row) * 1024 + k0 + c * 8], &As[base * 64]);
            gld16(&B[(size_t)(n0 + row) * 1024 + k0 + c * 8], &Bs[base * 64]);
        }
    };

    issue(0);
    f32x4 acc[4][4] = {};

    for (int t = 0; t < 16; ++t) {
        __syncthreads();                 // drains gld(t): LDS valid
        for (int ks = 0; ks < 2; ++ks) {
            bf16x8 af[4], bfm[4];
            for (int mi = 0; mi < 4; ++mi) {
                int row = rowb + mi * 16 + ln;
                af[mi] = *(const bf16x8*)&As[row * 64 + ((ks * 4 + g) ^ (ln & 7)) * 8];
            }
            for (int ni = 0; ni < 4; ++ni) {
                int row = colb + ni * 16 + ln;
                bfm[ni] = *(const bf16x8*)&Bs[row * 64 + ((ks * 4 + g) ^ (ln & 7)) * 8];
            }
            for (int mi = 0; mi < 4; ++mi)
                for (int ni = 0; ni < 4; ++ni)
                    acc[mi][ni] = MFMA16(af[mi], bfm[ni], acc[mi][ni]);
        }
        __syncthreads();                 // all waves done reading tile t
        if (t < 15) issue(t + 1);
    }

    if (proj != 2) {
        for (int mi = 0; mi < 4; ++mi) {
            for (int ni = 0; ni < 4; ++ni) {
                int col = n0 + colb + ni * 16 + ln;
                float bv_ = bias[col];
                int rowbase = m0 + rowb + mi * 16 + g * 4;
                if (proj == 0) {
                    for (int r = 0; r < 4; ++r)
                        Qp[(size_t)(rowbase + r) * 1024 + col] =
                            (bf16)((acc[mi][ni][r] + bv_) * QSCALE);
                } else {
                    for (int r = 0; r < 4; ++r)
                        Kp[(size_t)(rowbase + r) * 1024 + col] =
                            (bf16)(acc[mi][ni][r] + bv_);
                }
            }
        }
    } else {
        for (int mi = 0; mi < 4; ++mi) {
            for (int ni = 0; ni < 4; ++ni) {
                int col = colb + ni * 16 + ln;
                float bv_ = bias[n0 + col];
                int row = rowb + mi * 16 + g * 4;
                bf16x4 pk;
                for (int r = 0; r < 4; ++r) pk[r] = (bf16)(acc[mi][ni][r] + bv_);
                *(bf16x4*)&Ts[col * 132 + row] = pk;
            }
        }
        __syncthreads();
        const int bidx = m0 >> 11;
        const int tok0 = m0 & 2047;
        for (int i = 0; i < 8; ++i) {
            int c    = tid + 256 * i;
            int col  = c >> 4;
            int t64  = (c >> 3) & 1;
            int cc   = c & 7;
            int gcol = n0 + col;
            union { bf16 e[8]; uint4 u; } tmp;
            for (int j = 0; j < 8; ++j) {
                int s = 2 * cc + (j >> 2) + ((j & 3) << 4);
                tmp.e[j] = Ts[col * 132 + t64 * 64 + s];
            }
            size_t dst = ((size_t)(bidx * 16 + (gcol >> 6)) * 64 + (gcol & 63)) * 2048
                         + tok0 + t64 * 64 + cc * 8;
            *(uint4*)&Vt[dst] = tmp.u;
        }
    }
}

// ---------------------------------------------------------------------------
// Fallback QKV (ws too small): r7's fp32-A register staging + bf16-B gld16.
// ---------------------------------------------------------------------------
__global__ __launch_bounds__(256) void qkv_gemm(
    const float* __restrict__ q, const float* __restrict__ k,
    const float* __restrict__ v,
    const bf16* __restrict__ wq, const float* __restrict__ bq,
    const bf16* __restrict__ wk, const float* __restrict__ bk,
    const bf16* __restrict__ wv, const float* __restrict__ bv,
    bf16* __restrict__ Qp, bf16* __restrict__ Kp, bf16* __restrict__ Vt)
{
    __shared__ __align__(16) bf16 sm[8192 + 2 * 8192];
    bf16* As = sm;
    bf16* Bs = sm + 8192;
    bf16* Ts = sm;

    const int id  = blockIdx.x;
    const int pr  = (id >> 6) * 8 + (id & 7);
    const int proj = pr >> 5;
    const int m0  = (pr & 31) * 128;
    const int n0  = ((id >> 3) & 7) * 128;

    const float* A    = proj == 0 ? q  : proj == 1 ? k  : v;
    const bf16*  B    = proj == 0 ? wq : proj == 1 ? wk : wv;
    const float* bias = proj == 0 ? bq : proj == 1 ? bk : bv;

    const int tid  = threadIdx.x;
    const int lane = tid & 63;
    const int w    = tid >> 6;
    const int g    = lane >> 4;
    const int ln   = lane & 15;
    const int rowb = (w & 1) * 64;
    const int colb = (w >> 1) * 64;
    const int srow = tid >> 3, slc = tid & 7;
    const int ro   = lane >> 3, lc = lane & 7;

    float4 ra[4][2];
    for (int i = 0; i < 4; ++i) {
        const float* p = &A[(size_t)(m0 + srow + 32 * i) * 1024 + slc * 8];
        ra[i][0] = *(const float4*)p;
        ra[i][1] = *(const float4*)(p + 4);
    }
    for (int j = 0; j < 4; ++j) {
        int base = w * 32 + j * 8;
        int row  = base + ro;
        int c    = lc ^ (row & 7);
        gld16(&B[(size_t)(n0 + row) * 1024 + c * 8], &Bs[base * 64]);
    }

    f32x4 acc[4][4] = {};

    for (int t = 0; t < 16; ++t) {
        __syncthreads();
        for (int i = 0; i < 4; ++i) {
            int row = srow + 32 * i;
            *(bf16x8*)&As[row * 64 + (slc ^ (row & 7)) * 8] = cvt8(ra[i][0], ra[i][1]);
        }
        __syncthreads();
        if (t < 15) {
            int k1 = (t + 1) * 64;
            for (int i = 0; i < 4; ++i) {
                const float* p = &A[(size_t)(m0 + srow + 32 * i) * 1024 + k1 + slc * 8];
                ra[i][0] = *(const float4*)p;
                ra[i][1] = *(const float4*)(p + 4);
            }
            int bsel = (t + 1) & 1;
            for (int j = 0; j < 4; ++j) {
                int base = w * 32 + j * 8;
                int row  = base + ro;
                int c    = lc ^ (row & 7);
                gld16(&B[(size_t)(n0 + row) * 1024 + k1 + c * 8],
                      &Bs[bsel * 8192 + base * 64]);
            }
        }
        const bf16* Bt = Bs + (t & 1) * 8192;
        for (int ks = 0; ks < 2; ++ks) {
            bf16x8 af[4], bfm[4];
            for (int mi = 0; mi < 4; ++mi) {
                int row = rowb + mi * 16 + ln;
                af[mi] = *(const bf16x8*)&As[row * 64 + ((ks * 4 + g) ^ (ln & 7)) * 8];
            }
            for (int ni = 0; ni < 4; ++ni) {
                int row = colb + ni * 16 + ln;
                bfm[ni] = *(const bf16x8*)&Bt[row * 64 + ((ks * 4 + g) ^ (ln & 7)) * 8];
            }
            for (int mi = 0; mi < 4; ++mi)
                for (int ni = 0; ni < 4; ++ni)
                    acc[mi][ni] = MFMA16(af[mi], bfm[ni], acc[mi][ni]);
        }
    }

    if (proj != 2) {
        for (int mi = 0; mi < 4; ++mi) {
            for (int ni = 0; ni < 4; ++ni) {
                int col = n0 + colb + ni * 16 + ln;
                float bv_ = bias[col];
                int rowbase = m0 + rowb + mi * 16 + g * 4;
                if (proj == 0) {
                    for (int r = 0; r < 4; ++r)
                        Qp[(size_t)(rowbase + r) * 1024 + col] =
                            (bf16)((acc[mi][ni][r] + bv_) * QSCALE);
                } else {
                    for (int r = 0; r < 4; ++r)
                        Kp[(size_t)(rowbase + r) * 1024 + col] =
                            (bf16)(acc[mi][ni][r] + bv_);
                }
            }
        }
    } else {
        __syncthreads();
        for (int mi = 0; mi < 4; ++mi) {
            for (int ni = 0; ni < 4; ++ni) {
                int col = colb + ni * 16 + ln;
                float bv_ = bias[n0 + col];
                int row = rowb + mi * 16 + g * 4;
                bf16x4 pk;
                for (int r = 0; r < 4; ++r) pk[r] = (bf16)(acc[mi][ni][r] + bv_);
                *(bf16x4*)&Ts[col * 132 + row] = pk;
            }
        }
        __syncthreads();
        const int bidx = m0 >> 11;
        const int tok0 = m0 & 2047;
        for (int i = 0; i < 8; ++i) {
            int c    = tid + 256 * i;
            int col  = c >> 4;
            int t64  = (c >> 3) & 1;
            int cc   = c & 7;
            int gcol = n0 + col;
            union { bf16 e[8]; uint4 u; } tmp;
            for (int j = 0; j < 8; ++j) {
                int s = 2 * cc + (j >> 2) + ((j & 3) << 4);
                tmp.e[j] = Ts[col * 132 + t64 * 64 + s];
            }
            size_t dst = ((size_t)(bidx * 16 + (gcol >> 6)) * 64 + (gcol & 63)) * 2048
                         + tok0 + t64 * 64 + cc * 8;
            *(uint4*)&Vt[dst] = tmp.u;
        }
    }
}

// ---------------------------------------------------------------------------
// Output projection: C[4096,1024] fp32 = Ctx(bf16) @ wo^T(bf16) + bo.
// 64x128 tiles, grid 512, both operands dbuf global_load_lds, 1 barrier/iter.
// ---------------------------------------------------------------------------
__global__ __launch_bounds__(256) void gemm_out(
    const bf16* __restrict__ A, const bf16* __restrict__ B,
    const float* __restrict__ bias, float* __restrict__ C)
{
    __shared__ __align__(16) bf16 sm[2 * 4096 + 2 * 8192];
    bf16* As = sm;
    bf16* Bs = sm + 8192;

    const int id = blockIdx.x;
    const int m0 = ((id >> 6) * 8 + (id & 7)) * 64;
    const int n0 = ((id >> 3) & 7) * 128;

    const int tid  = threadIdx.x;
    const int lane = tid & 63;
    const int w    = tid >> 6;
    const int g    = lane >> 4;
    const int ln   = lane & 15;
    const int rowb = (w & 1) * 32;
    const int colb = (w >> 1) * 64;
    const int ro   = lane >> 3, lc = lane & 7;

    auto issue = [&](int t) {
        int k0 = t * 64, sel = t & 1;
        for (int j = 0; j < 2; ++j) {
            int base = w * 16 + j * 8;
            int row  = base + ro;
            int c    = lc ^ (row & 7);
            gld16(&A[(size_t)(m0 + row) * 1024 + k0 + c * 8],
                  &As[sel * 4096 + base * 64]);
        }
        for (int j = 0; j < 4; ++j) {
            int base = w * 32 + j * 8;
            int row  = base + ro;
            int c    = lc ^ (row & 7);
            gld16(&B[(size_t)(n0 + row) * 1024 + k0 + c * 8],
                  &Bs[sel * 8192 + base * 64]);
        }
    };

    issue(0);
    f32x4 acc[2][4] = {};

    for (int t = 0; t < 16; ++t) {
        __syncthreads();
        if (t < 15) issue(t + 1);
        const bf16* At = As + (t & 1) * 4096;
        const bf16* Bt = Bs + (t & 1) * 8192;
        for (int ks = 0; ks < 2; ++ks) {
            bf16x8 af[2], bfm[4];
            for (int mi = 0; mi < 2; ++mi) {
                int row = rowb + mi * 16 + ln;
                af[mi] = *(const bf16x8*)&At[row * 64 + ((ks * 4 + g) ^ (ln & 7)) * 8];
            }
            for (int ni = 0; ni < 4; ++ni) {
                int row = colb + ni * 16 + ln;
                bfm[ni] = *(const bf16x8*)&Bt[row * 64 + ((ks * 4 + g) ^ (ln & 7)) * 8];
            }
            for (int mi = 0; mi < 2; ++mi)
                for (int ni = 0; ni < 4; ++ni)
                    acc[mi][ni] = MFMA16(af[mi], bfm[ni], acc[mi][ni]);
        }
    }

    for (int mi = 0; mi < 2; ++mi) {
        for (int ni = 0; ni < 4; ++ni) {
            int col = n0 + colb + ni * 16 + ln;
            float bv_ = bias[col];
            int rowbase = m0 + rowb + mi * 16 + g * 4;
            for (int r = 0; r < 4; ++r)
                C[(size_t)(rowbase + r) * 1024 + col] = acc[mi][ni][r] + bv_;
        }
    }
}

// ---------------------------------------------------------------------------
// Flash attention (no-max softmax; logits pre-scaled -> exp2). 64-row q-tiles,
// grid 1024 = 4 blocks/CU (LDS 40 KiB), XCD-swizzled so all 32 q-tiles of one
// (b,h) share an XCD L2 for K/V. K/V dbuf via gld16, 1 barrier per KV tile.
// V pre-permuted (kv' = (s&15)*4+(s>>4)); P packed b64 xor-swizzled.
// ---------------------------------------------------------------------------
__global__ __launch_bounds__(256) void attn_kernel(
    const bf16* __restrict__ Qp, const bf16* __restrict__ Kp,
    const bf16* __restrict__ Vt, bf16* __restrict__ Ctx)
{
    __shared__ __align__(16) bf16 smem[4096 + 2 * 4096 + 2 * 4096];
    bf16* Ps = smem;               // [64][64] swizzled; aliases Qs
    bf16* Qs = smem;
    bf16* Ks = smem + 4096;        // 2 x [64][64]  [kv][d]
    bf16* Vs = smem + 12288;       // 2 x [64][64]  [d][kv']

    const int id = blockIdx.x;
    const int qt = (id >> 3) & 31;                 // 0..31 (64-row tiles)
    const int bh = (id & 7) + ((id >> 8) << 3);    // 0..31, id%8 = XCD

    const int tid  = threadIdx.x;
    const int lane = tid & 63;
    const int w    = tid >> 6;
    const int g    = lane >> 4;
    const int ln   = lane & 15;
    const int ro   = lane >> 3, lc = lane & 7;
    const size_t rowQ0 = (size_t)(bh >> 4) * 2048 + qt * 64;
    const size_t rowK0 = (size_t)(bh >> 4) * 2048;
    const int hcol = (bh & 15) * 64;
    const bf16* VtB = Vt + (size_t)bh * 64 * 2048;

    // stage Q (wave-private 16 rows each) and K/V tile 0
    for (int j = 0; j < 2; ++j) {
        int base = w * 16 + j * 8;
        int row  = base + ro;
        int c    = lc ^ (row & 7);
        gld16(&Qp[(rowQ0 + row) * 1024 + hcol + c * 8], &Qs[base * 64]);
        gld16(&Kp[(rowK0 + row) * 1024 + hcol + c * 8], &Ks[base * 64]);
        gld16(&VtB[(size_t)row * 2048 + c * 8], &Vs[base * 64]);
    }
    __syncthreads();

    bf16x8 qf[2];
    for (int ks = 0; ks < 2; ++ks) {
        int row = w * 16 + ln;
        qf[ks] = *(const bf16x8*)&Qs[row * 64 + ((ks * 4 + g) ^ (ln & 7)) * 8];
    }

    f32x4 oacc[4] = {};
    float l_part[4] = {};

    for (int t = 0; t < 32; ++t) {
        if (t < 31) {                  // t+1 KV flies through this tile's compute
            int sel = (t + 1) & 1, kvo = (t + 1) * 64;
            for (int j = 0; j < 2; ++j) {
                int base = w * 16 + j * 8;
                int kv   = base + ro;
                int c    = lc ^ (kv & 7);
                gld16(&Kp[(rowK0 + kvo + kv) * 1024 + hcol + c * 8],
                      &Ks[sel * 4096 + base * 64]);
                gld16(&VtB[(size_t)kv * 2048 + kvo + c * 8],
                      &Vs[sel * 4096 + base * 64]);
            }
        }
        const bf16* Kt  = Ks + (t & 1) * 4096;
        const bf16* Vti = Vs + (t & 1) * 4096;

        // S = Q K^T (pre-scaled)
        f32x4 sf[4] = {};
        for (int ks = 0; ks < 2; ++ks) {
            bf16x8 kf[4];
            for (int nj = 0; nj < 4; ++nj) {
                int row = nj * 16 + ln;
                kf[nj] = *(const bf16x8*)&Kt[row * 64 + ((ks * 4 + g) ^ (ln & 7)) * 8];
            }
            for (int nj = 0; nj < 4; ++nj)
                sf[nj] = MFMA16(qf[ks], kf[nj], sf[nj]);
        }

        // P = exp2(S), packed b64 store (wave-private rows)
        for (int r = 0; r < 4; ++r) {
            float p0 = __builtin_amdgcn_exp2f(sf[0][r]);
            float p1 = __builtin_amdgcn_exp2f(sf[1][r]);
            float p2 = __builtin_amdgcn_exp2f(sf[2][r]);
            float p3 = __builtin_amdgcn_exp2f(sf[3][r]);
            l_part[r] += (p0 + p1) + (p2 + p3);
            int qrow = w * 16 + g * 4 + r;
            int slot = ln ^ ((qrow & 7) << 1);
            bf16x4 pk;
            pk[0] = (bf16)p0; pk[1] = (bf16)p1; pk[2] = (bf16)p2; pk[3] = (bf16)p3;
            *(bf16x4*)&Ps[qrow * 64 + slot * 4] = pk;
        }

        // O += P V
        for (int ks = 0; ks < 2; ++ks) {
            bf16x8 pf, vf[4];
            {
                int row = w * 16 + ln;
                int p = (ks * 8 + g * 2) ^ ((row & 7) << 1);
                pf = *(const bf16x8*)&Ps[row * 64 + p * 4];
            }
            for (int nd = 0; nd < 4; ++nd) {
                int row = nd * 16 + ln;
                vf[nd] = *(const bf16x8*)&Vti[row * 64 + ((ks * 4 + g) ^ (ln & 7)) * 8];
            }
            for (int nd = 0; nd < 4; ++nd)
                oacc[nd] = MFMA16(pf, vf[nd], oacc[nd]);
        }
        __syncthreads();   // drains t+1 KV loads; buffer swap safe
    }

    // epilogue: row-sum reduction (16-lane groups), normalize, store
    for (int r = 0; r < 4; ++r) {
        float l = l_part[r];
        for (int off = 8; off >= 1; off >>= 1)
            l += __shfl_xor(l, off, 64);
        float inv = 1.0f / l;
        size_t row = rowQ0 + w * 16 + g * 4 + r;
        for (int nd = 0; nd < 4; ++nd)
            Ctx[row * 1024 + hcol + nd * 16 + ln] = (bf16)(oacc[nd][r] * inv);
    }
}

extern "C" void kernel_launch(void* const* d_in, const int* in_sizes, int n_in,
                              void* d_out, int out_size, void* d_ws, size_t ws_size,
                              hipStream_t stream)
{
    const float* q  = (const float*)d_in[0];
    const float* k  = (const float*)d_in[1];
    const float* v  = (const float*)d_in[2];
    const float* wq = (const float*)d_in[3];
    const float* bq = (const float*)d_in[4];
    const float* wk = (const float*)d_in[5];
    const float* bk = (const float*)d_in[6];
    const float* wv = (const float*)d_in[7];
    const float* bv = (const float*)d_in[8];
    const float* wo = (const float*)d_in[9];
    const float* bo = (const float*)d_in[10];
    float* out = (float*)d_out;

    const int D = 1024;
    bf16* W  = (bf16*)d_ws;
    bf16* Qp = W;                            // 8 MB
    bf16* Kp = W + (1u << 22);               // 8 MB
    bf16* Vt = W + (2u << 22);               // 8 MB, [bh][d][tok']
    bf16* Ctx = Qp;   // alias: each attn block overwrites only its consumed Q

    if (ws_size >= (size_t)40 * 1024 * 1024) {
        // fast path: everything bf16 up front
        bf16* vb  = W + (3u << 22);          // 8 MB
        bf16* wqb = W + (1u << 24);          // 2 MB
        bf16* wkb = wqb + (1u << 20);
        bf16* wvb = wkb + (1u << 20);
        bf16* wob = wvb + (1u << 20);
        bf16* qb  = (bf16*)d_out;            // d_out scratch (overwritten later)
        bf16* kb  = qb + (1u << 22);

        cvt7_kernel<<<dim3(2048, 7), 256, 0, stream>>>(
            q, qb, k, kb, v, vb, wq, wqb, wk, wkb, wv, wvb, wo, wob);
        qkv_bf16<<<768, 256, 0, stream>>>(qb, kb, vb, wqb, bq, wkb, bk, wvb, bv,
                                          Qp, Kp, Vt);
        attn_kernel<<<1024, 256, 0, stream>>>(Qp, Kp, Vt, Ctx);
        gemm_out<<<512, 256, 0, stream>>>(Ctx, wob, bo, out);
    } else {
        // fallback (ws < 40 MB): r7 structure
        bf16* wqb = (bf16*)d_out;
        bf16* wkb = wqb + (size_t)D * D;
        bf16* wvb = wkb + (size_t)D * D;
        bf16* wob = Kp;                      // dead after attn

        cvt3_kernel<<<dim3(512, 3), 256, 0, stream>>>(wq, wqb, wk, wkb, wv, wvb);
        qkv_gemm<<<768, 256, 0, stream>>>(q, k, v, wqb, bq, wkb, bk, wvb, bv,
                                          Qp, Kp, Vt);
        attn_kernel<<<1024, 256, 0, stream>>>(Qp, Kp, Vt, Ctx);
        cvt_kernel<<<512, 256, 0, stream>>>(wo, wob, D * D);
        gemm_out<<<512, 256, 0, stream>>>(Ctx, wob, bo, out);
    }
}